// Round 1
// baseline (2108.404 us; speedup 1.0000x reference)
//
#include <hip/hip_runtime.h>

#define B_   2
#define S_   1024
#define D_   1024
#define H_   16
#define HD_  64
#define L_   4
#define MFF  2730
#define MPAD 2816
#define V_   32000

typedef __attribute__((ext_vector_type(8))) short   short8;
typedef __attribute__((ext_vector_type(4))) float   floatx4;

__device__ __forceinline__ unsigned short f2b(float f) {
  unsigned u = __float_as_uint(f);
  u += 0x7fffu + ((u >> 16) & 1u);
  return (unsigned short)(u >> 16);
}
__device__ __forceinline__ float b2f(unsigned short s) {
  return __uint_as_float(((unsigned)s) << 16);
}

// ---------------- embed gather ----------------
__global__ __launch_bounds__(256) void embed_kernel(const int* __restrict__ tokens,
                                                    const float* __restrict__ embed,
                                                    float* __restrict__ x) {
  int row = blockIdx.x;                 // 0..2047 (b*S+s)
  int tok = tokens[row];
  int c = threadIdx.x * 4;
  float4 v = *(const float4*)&embed[(size_t)tok * D_ + c];
  *(float4*)&x[(size_t)row * D_ + c] = v;
}

// ---------------- rmsnorm (f32 in -> bf16 out) ----------------
__global__ __launch_bounds__(256) void rmsnorm_bf(const float* __restrict__ x,
                                                  const float* __restrict__ w,
                                                  unsigned short* __restrict__ out) {
  int row = blockIdx.x, t = threadIdx.x;
  float4 xv = *(const float4*)&x[(size_t)row * D_ + t * 4];
  float ss = xv.x * xv.x + xv.y * xv.y + xv.z * xv.z + xv.w * xv.w;
  #pragma unroll
  for (int off = 1; off < 64; off <<= 1) ss += __shfl_xor(ss, off, 64);
  __shared__ float sred[4];
  if ((t & 63) == 0) sred[t >> 6] = ss;
  __syncthreads();
  ss = sred[0] + sred[1] + sred[2] + sred[3];
  float rr = rsqrtf(ss * (1.f / (float)D_) + 1e-6f);
  float4 wv = *(const float4*)&w[t * 4];
  size_t o = (size_t)row * D_ + t * 4;
  out[o + 0] = f2b(xv.x * rr * wv.x);
  out[o + 1] = f2b(xv.y * rr * wv.y);
  out[o + 2] = f2b(xv.z * rr * wv.z);
  out[o + 3] = f2b(xv.w * rr * wv.w);
}

// ---------------- final rmsnorm (last token rows, f32 out) ----------------
__global__ __launch_bounds__(256) void rmsnorm_final(const float* __restrict__ x,
                                                     const float* __restrict__ w,
                                                     float* __restrict__ out) {
  int b = blockIdx.x, t = threadIdx.x;
  const float* xr = x + ((size_t)b * S_ + (S_ - 1)) * D_;
  float4 xv = *(const float4*)&xr[t * 4];
  float ss = xv.x * xv.x + xv.y * xv.y + xv.z * xv.z + xv.w * xv.w;
  #pragma unroll
  for (int off = 1; off < 64; off <<= 1) ss += __shfl_xor(ss, off, 64);
  __shared__ float sred[4];
  if ((t & 63) == 0) sred[t >> 6] = ss;
  __syncthreads();
  ss = sred[0] + sred[1] + sred[2] + sred[3];
  float rr = rsqrtf(ss * (1.f / (float)D_) + 1e-6f);
  float4 wv = *(const float4*)&w[t * 4];
  size_t o = (size_t)b * D_ + t * 4;
  out[o + 0] = xv.x * rr * wv.x;
  out[o + 1] = xv.y * rr * wv.y;
  out[o + 2] = xv.z * rr * wv.z;
  out[o + 3] = xv.w * rr * wv.w;
}

// ---------------- weight transpose + f32->bf16 (K x N -> Npad x Kpad) ----------------
__global__ __launch_bounds__(256) void transpose_conv(const float* __restrict__ W,
                                                      unsigned short* __restrict__ Wt,
                                                      int K, int N, int Kpad, int Npad) {
  __shared__ float tile[32][33];
  int tx = threadIdx.x & 31, ty = threadIdx.x >> 5;  // ty 0..7
  int k0 = blockIdx.y * 32, n0 = blockIdx.x * 32;
  #pragma unroll
  for (int i = 0; i < 4; i++) {
    int kk = k0 + ty + i * 8, nn = n0 + tx;
    tile[ty + i * 8][tx] = (kk < K && nn < N) ? W[(size_t)kk * N + nn] : 0.f;
  }
  __syncthreads();
  #pragma unroll
  for (int i = 0; i < 4; i++) {
    int nn = n0 + ty + i * 8, kk = k0 + tx;
    if (nn < Npad && kk < Kpad)
      Wt[(size_t)nn * Kpad + kk] = f2b(tile[tx][ty + i * 8]);
  }
}

// ---------------- bf16 MFMA GEMM, A[M][K] bf16, B^T[N][K] bf16, 128x128 tile ----------
// EPI: 0 = f32 out (acc+bias), 1 = f32 out (acc+bias+res), 2 = bf16 out (acc+bias)
template <int EPI>
__global__ __launch_bounds__(256) void gemm_bt(const unsigned short* __restrict__ A,
                                               const unsigned short* __restrict__ B,
                                               const float* __restrict__ bias,
                                               const float* __restrict__ res,
                                               void* __restrict__ Cout,
                                               int N, int K, int lda, int ldb, int ldc,
                                               int Nlog) {
  __shared__ unsigned short As[128 * 32];
  __shared__ unsigned short Bs[128 * 32];
  const int tid = threadIdx.x;
  const int lane = tid & 63, wave = tid >> 6;
  const int m0 = blockIdx.y * 128, n0 = blockIdx.x * 128;
  const int rS = tid >> 2;               // staging row 0..63
  const int kS = (tid & 3) * 8;          // staging k offset {0,8,16,24}
  const int fr = lane & 15;              // frag row/col index
  const int kq = (lane >> 4) * 8;        // frag k offset
  const int wm = (wave & 1) * 64, wn = (wave >> 1) * 64;

  floatx4 zv = {0.f, 0.f, 0.f, 0.f};
  floatx4 acc[4][4];
  #pragma unroll
  for (int mi = 0; mi < 4; mi++)
    #pragma unroll
    for (int ni = 0; ni < 4; ni++) acc[mi][ni] = zv;

  for (int k0 = 0; k0 < K; k0 += 32) {
    __syncthreads();
    uint4 a0 = *(const uint4*)(A + (size_t)(m0 + rS) * lda + k0 + kS);
    uint4 a1 = *(const uint4*)(A + (size_t)(m0 + rS + 64) * lda + k0 + kS);
    uint4 b0 = *(const uint4*)(B + (size_t)(n0 + rS) * ldb + k0 + kS);
    uint4 b1 = *(const uint4*)(B + (size_t)(n0 + rS + 64) * ldb + k0 + kS);
    *(uint4*)&As[rS * 32 + kS] = a0;
    *(uint4*)&As[(rS + 64) * 32 + kS] = a1;
    *(uint4*)&Bs[rS * 32 + kS] = b0;
    *(uint4*)&Bs[(rS + 64) * 32 + kS] = b1;
    __syncthreads();
    short8 af[4], bfv[4];
    #pragma unroll
    for (int mi = 0; mi < 4; mi++) af[mi] = *(const short8*)&As[(wm + mi * 16 + fr) * 32 + kq];
    #pragma unroll
    for (int ni = 0; ni < 4; ni++) bfv[ni] = *(const short8*)&Bs[(wn + ni * 16 + fr) * 32 + kq];
    #pragma unroll
    for (int mi = 0; mi < 4; mi++)
      #pragma unroll
      for (int ni = 0; ni < 4; ni++)
        acc[mi][ni] = __builtin_amdgcn_mfma_f32_16x16x32_bf16(af[mi], bfv[ni], acc[mi][ni], 0, 0, 0);
  }

  const int cr = (lane >> 4) * 4;  // C/D row base within 16x16
  const int cc = lane & 15;        // C/D col within 16x16
  #pragma unroll
  for (int mi = 0; mi < 4; mi++) {
    #pragma unroll
    for (int ni = 0; ni < 4; ni++) {
      int col = n0 + wn + ni * 16 + cc;
      float bv = (col < Nlog) ? bias[col] : 0.f;
      #pragma unroll
      for (int r = 0; r < 4; r++) {
        int row = m0 + wm + mi * 16 + cr + r;
        float val = acc[mi][ni][r] + bv;
        if constexpr (EPI == 1) val += res[(size_t)row * ldc + col];
        if constexpr (EPI == 2)
          ((unsigned short*)Cout)[(size_t)row * ldc + col] = f2b(val);
        else
          ((float*)Cout)[(size_t)row * ldc + col] = val;
      }
    }
  }
}

// ---------------- rope table (double precision) ----------------
__global__ __launch_bounds__(256) void rope_table(float* __restrict__ cs, float* __restrict__ sn) {
  int i = blockIdx.x * 256 + threadIdx.x;  // S*32
  int s = i >> 5, f = i & 31;
  double inv = pow(10000.0, -(double)(2 * f) / 64.0);
  double ang = (double)s * inv;
  cs[i] = (float)cos(ang);
  sn[i] = (float)sin(ang);
}

// ---------------- rope apply + transpose (qkv f32 -> q,k,v f32 (B*H,S,HD)) ----------
__global__ __launch_bounds__(256) void rope_apply(const float* __restrict__ qkv,
                                                  const float* __restrict__ cs,
                                                  const float* __restrict__ sn,
                                                  float* __restrict__ q,
                                                  float* __restrict__ k,
                                                  float* __restrict__ v) {
  int i = blockIdx.x * 256 + threadIdx.x;  // B*S*H*32 = 1048576
  int pr = i & 31;
  int h  = (i >> 5) & 15;
  int s  = (i >> 9) & 1023;
  int b  = i >> 19;
  size_t base = ((size_t)(b * S_ + s)) * (3 * D_) + h * HD_ + pr * 2;
  float qe = qkv[base],            qo = qkv[base + 1];
  float ke = qkv[base + D_],       ko = qkv[base + D_ + 1];
  float ve = qkv[base + 2 * D_],   vo = qkv[base + 2 * D_ + 1];
  float c = cs[s * 32 + pr], sv = sn[s * 32 + pr];
  size_t ob = ((size_t)(b * H_ + h)) * (S_ * HD_) + (size_t)s * HD_ + pr * 2;
  q[ob] = qe * c - qo * sv;  q[ob + 1] = qe * sv + qo * c;
  k[ob] = ke * c - ko * sv;  k[ob + 1] = ke * sv + ko * c;
  v[ob] = ve;                v[ob + 1] = vo;
}

// ---------------- attention (flash-style, vector f32), out bf16 (B,S,D) ----------
#define APAD 68
__global__ __launch_bounds__(256) void attn_kernel(const float* __restrict__ qg,
                                                   const float* __restrict__ kg,
                                                   const float* __restrict__ vg,
                                                   unsigned short* __restrict__ o) {
  __shared__ float qs[64 * APAD], ks[64 * APAD], vs[64 * APAD], ps[64 * APAD];
  int qt = blockIdx.x, bh = blockIdx.y;
  int b = bh >> 4, h = bh & 15;
  const float* qb = qg + (size_t)bh * (S_ * HD_);
  const float* kb = kg + (size_t)bh * (S_ * HD_);
  const float* vb = vg + (size_t)bh * (S_ * HD_);
  int tid = threadIdx.x, lane = tid & 63, wave = tid >> 6;

  {  // stage q tile
    int row = tid >> 2, c0 = (tid & 3) * 16;
    #pragma unroll
    for (int i = 0; i < 4; i++)
      *(float4*)&qs[row * APAD + c0 + i * 4] = *(const float4*)&qb[(qt * 64 + row) * HD_ + c0 + i * 4];
  }
  int r0 = wave * 16 + ((lane >> 4) << 2);  // 4 rows
  int cg = (lane & 15) * 4;                 // 4 cols (scores) / 4 dims (output)
  float m_run[4], l_run[4];
  float4 oa[4];
  #pragma unroll
  for (int rr = 0; rr < 4; rr++) {
    m_run[rr] = -1e30f; l_run[rr] = 0.f; oa[rr] = make_float4(0.f, 0.f, 0.f, 0.f);
  }
  __syncthreads();

  for (int kt = 0; kt <= qt; kt++) {
    {  // stage k,v tiles
      int row = tid >> 2, c0 = (tid & 3) * 16;
      #pragma unroll
      for (int i = 0; i < 4; i++) {
        *(float4*)&ks[row * APAD + c0 + i * 4] = *(const float4*)&kb[(kt * 64 + row) * HD_ + c0 + i * 4];
        *(float4*)&vs[row * APAD + c0 + i * 4] = *(const float4*)&vb[(kt * 64 + row) * HD_ + c0 + i * 4];
      }
    }
    __syncthreads();
    float s[4][4] = {};
    #pragma unroll
    for (int dc = 0; dc < 16; dc++) {
      float4 qv[4], kv[4];
      #pragma unroll
      for (int rr = 0; rr < 4; rr++) qv[rr] = *(const float4*)&qs[(r0 + rr) * APAD + dc * 4];
      #pragma unroll
      for (int jj = 0; jj < 4; jj++) kv[jj] = *(const float4*)&ks[(cg + jj) * APAD + dc * 4];
      #pragma unroll
      for (int rr = 0; rr < 4; rr++)
        #pragma unroll
        for (int jj = 0; jj < 4; jj++)
          s[rr][jj] += qv[rr].x * kv[jj].x + qv[rr].y * kv[jj].y + qv[rr].z * kv[jj].z + qv[rr].w * kv[jj].w;
    }
    int qrow_base = qt * 64 + r0, col_base = kt * 64 + cg;
    #pragma unroll
    for (int rr = 0; rr < 4; rr++) {
      #pragma unroll
      for (int jj = 0; jj < 4; jj++) {
        float sv = s[rr][jj] * 0.125f;
        if (col_base + jj > qrow_base + rr) sv = -1e9f;
        s[rr][jj] = sv;
      }
      float mx = fmaxf(fmaxf(s[rr][0], s[rr][1]), fmaxf(s[rr][2], s[rr][3]));
      #pragma unroll
      for (int off = 1; off < 16; off <<= 1) mx = fmaxf(mx, __shfl_xor(mx, off, 64));
      float mn = fmaxf(m_run[rr], mx);
      float alpha = __expf(m_run[rr] - mn);
      float rs = 0.f;
      #pragma unroll
      for (int jj = 0; jj < 4; jj++) { float pv = __expf(s[rr][jj] - mn); s[rr][jj] = pv; rs += pv; }
      #pragma unroll
      for (int off = 1; off < 16; off <<= 1) rs += __shfl_xor(rs, off, 64);
      l_run[rr] = l_run[rr] * alpha + rs;
      m_run[rr] = mn;
      oa[rr].x *= alpha; oa[rr].y *= alpha; oa[rr].z *= alpha; oa[rr].w *= alpha;
      #pragma unroll
      for (int jj = 0; jj < 4; jj++) ps[(r0 + rr) * APAD + cg + jj] = s[rr][jj];
    }
    __syncthreads();
    #pragma unroll 4
    for (int j = 0; j < 64; j++) {
      float4 vv = *(const float4*)&vs[j * APAD + cg];
      #pragma unroll
      for (int rr = 0; rr < 4; rr++) {
        float pv = ps[(r0 + rr) * APAD + j];
        oa[rr].x += pv * vv.x; oa[rr].y += pv * vv.y; oa[rr].z += pv * vv.z; oa[rr].w += pv * vv.w;
      }
    }
    __syncthreads();
  }
  #pragma unroll
  for (int rr = 0; rr < 4; rr++) {
    float inv = 1.f / l_run[rr];
    int srow = qt * 64 + r0 + rr;
    size_t base = ((size_t)(b * S_ + srow)) * D_ + h * HD_ + cg;
    o[base + 0] = f2b(oa[rr].x * inv);
    o[base + 1] = f2b(oa[rr].y * inv);
    o[base + 2] = f2b(oa[rr].z * inv);
    o[base + 3] = f2b(oa[rr].w * inv);
  }
}

// ---------------- swiglu elementwise: act = silu(g)*u (bf16), zero pad ----------
__global__ __launch_bounds__(256) void swiglu_kernel(const unsigned short* __restrict__ g,
                                                     const unsigned short* __restrict__ u,
                                                     unsigned short* __restrict__ act) {
  int n = blockIdx.x * 256 + threadIdx.x;  // 0..2815
  int row = blockIdx.y;
  size_t idx = (size_t)row * MPAD + n;
  float a = 0.f;
  if (n < MFF) {
    float gv = b2f(g[idx]);
    float uv = b2f(u[idx]);
    a = gv / (1.f + __expf(-gv)) * uv;
  }
  act[idx] = f2b(a);
}

// ---------------- head GEMV: out[b][v] = hf[b].Whead[:,v] + bhead[v] ----------
__global__ __launch_bounds__(64) void head_kernel(const float* __restrict__ hf,
                                                  const float* __restrict__ Wh,
                                                  const float* __restrict__ bh,
                                                  float* __restrict__ out) {
  __shared__ float hs[2 * D_];
  int t = threadIdx.x;
  #pragma unroll
  for (int i = 0; i < 32; i++) hs[i * 64 + t] = hf[i * 64 + t];
  __syncthreads();
  int v = blockIdx.x * 64 + t;
  float a0 = bh[v], a1 = bh[v];
  for (int k = 0; k < D_; k++) {
    float w = Wh[(size_t)k * V_ + v];
    a0 = fmaf(hs[k], w, a0);
    a1 = fmaf(hs[D_ + k], w, a1);
  }
  out[v] = a0;
  out[V_ + v] = a1;
}

// ======================= launcher =======================
extern "C" void kernel_launch(void* const* d_in, const int* in_sizes, int n_in,
                              void* d_out, int out_size, void* d_ws, size_t ws_size,
                              hipStream_t stream) {
  const int*   tokens = (const int*)d_in[0];
  const float* embed  = (const float*)d_in[1];
  const float* Wqkv   = (const float*)d_in[2];
  const float* bqkv   = (const float*)d_in[3];
  const float* Wout   = (const float*)d_in[4];
  const float* bout   = (const float*)d_in[5];
  const float* ln1    = (const float*)d_in[6];
  const float* ln2    = (const float*)d_in[7];
  const float* Wg     = (const float*)d_in[8];
  const float* bg     = (const float*)d_in[9];
  const float* Wu     = (const float*)d_in[10];
  const float* bu     = (const float*)d_in[11];
  const float* Wd     = (const float*)d_in[12];
  const float* bd     = (const float*)d_in[13];
  const float* lnf    = (const float*)d_in[14];
  const float* Whead  = (const float*)d_in[15];
  const float* bhead  = (const float*)d_in[16];
  float* out = (float*)d_out;

  char* base = (char*)d_ws;
  size_t off = 0;
  auto alloc = [&](size_t bytes) -> char* {
    char* r = base + off;
    off += (bytes + 255) & ~(size_t)255;
    return r;
  };
  const size_t NROW = (size_t)B_ * S_;  // 2048
  unsigned short* WqkvT = (unsigned short*)alloc((size_t)L_ * 3072 * 1024 * 2);
  unsigned short* WoutT = (unsigned short*)alloc((size_t)L_ * 1024 * 1024 * 2);
  unsigned short* WgT   = (unsigned short*)alloc((size_t)L_ * MPAD * 1024 * 2);
  unsigned short* WuT   = (unsigned short*)alloc((size_t)L_ * MPAD * 1024 * 2);
  unsigned short* WdT   = (unsigned short*)alloc((size_t)L_ * 1024 * MPAD * 2);
  float*          x     = (float*)alloc(NROW * D_ * 4);
  unsigned short* h     = (unsigned short*)alloc(NROW * D_ * 2);
  float*          qkv   = (float*)alloc(NROW * 3072 * 4);       // g/u alias into this
  float*          qbuf  = (float*)alloc(NROW * D_ * 4);
  float*          kbuf  = (float*)alloc(NROW * D_ * 4);
  float*          vbuf  = (float*)alloc(NROW * D_ * 4);         // act aliases q/k
  unsigned short* aout  = (unsigned short*)alloc(NROW * D_ * 2);
  float*          csT   = (float*)alloc((size_t)S_ * 32 * 4);
  float*          snT   = (float*)alloc((size_t)S_ * 32 * 4);
  float*          hfin  = (float*)alloc((size_t)B_ * D_ * 4);
  unsigned short* gbuf  = (unsigned short*)qkv;                       // 11.5MB
  unsigned short* ubuf  = (unsigned short*)qkv + NROW * MPAD;         // 11.5MB (fits in 24MB)
  unsigned short* act   = (unsigned short*)qbuf;                      // 11.5MB (q+k dead)

  // ---- weight transposes (per call; d_ws is re-poisoned every launch) ----
  for (int l = 0; l < L_; l++) {
    transpose_conv<<<dim3(3072 / 32, 1024 / 32), 256, 0, stream>>>(
        Wqkv + (size_t)l * 1024 * 3072, WqkvT + (size_t)l * 3072 * 1024, 1024, 3072, 1024, 3072);
    transpose_conv<<<dim3(1024 / 32, 1024 / 32), 256, 0, stream>>>(
        Wout + (size_t)l * 1024 * 1024, WoutT + (size_t)l * 1024 * 1024, 1024, 1024, 1024, 1024);
    transpose_conv<<<dim3(MPAD / 32, 1024 / 32), 256, 0, stream>>>(
        Wg + (size_t)l * 1024 * MFF, WgT + (size_t)l * MPAD * 1024, 1024, MFF, 1024, MPAD);
    transpose_conv<<<dim3(MPAD / 32, 1024 / 32), 256, 0, stream>>>(
        Wu + (size_t)l * 1024 * MFF, WuT + (size_t)l * MPAD * 1024, 1024, MFF, 1024, MPAD);
    transpose_conv<<<dim3(1024 / 32, MPAD / 32), 256, 0, stream>>>(
        Wd + (size_t)l * MFF * 1024, WdT + (size_t)l * 1024 * MPAD, MFF, 1024, MPAD, 1024);
  }
  rope_table<<<dim3(S_ * 32 / 256), 256, 0, stream>>>(csT, snT);
  embed_kernel<<<dim3(NROW), 256, 0, stream>>>(tokens, embed, x);

  for (int l = 0; l < L_; l++) {
    // h = rmsnorm(x, ln1)
    rmsnorm_bf<<<dim3(NROW), 256, 0, stream>>>(x, ln1 + (size_t)l * D_, h);
    // qkv = h @ Wqkv + bqkv
    gemm_bt<0><<<dim3(3072 / 128, NROW / 128), 256, 0, stream>>>(
        h, WqkvT + (size_t)l * 3072 * 1024, bqkv + (size_t)l * 3072, nullptr, qkv,
        3072, 1024, 1024, 1024, 3072, 3072);
    // rope + split
    rope_apply<<<dim3((B_ * S_ * H_ * 32) / 256), 256, 0, stream>>>(qkv, csT, snT, qbuf, kbuf, vbuf);
    // attention
    attn_kernel<<<dim3(S_ / 64, B_ * H_), 256, 0, stream>>>(qbuf, kbuf, vbuf, aout);
    // x += aout @ Wout + bout
    gemm_bt<1><<<dim3(1024 / 128, NROW / 128), 256, 0, stream>>>(
        aout, WoutT + (size_t)l * 1024 * 1024, bout + (size_t)l * D_, x, x,
        1024, 1024, 1024, 1024, 1024, 1024);
    // h = rmsnorm(x, ln2)
    rmsnorm_bf<<<dim3(NROW), 256, 0, stream>>>(x, ln2 + (size_t)l * D_, h);
    // g = h @ Wg + bg ; u = h @ Wu + bu  (bf16 out, padded N)
    gemm_bt<2><<<dim3(MPAD / 128, NROW / 128), 256, 0, stream>>>(
        h, WgT + (size_t)l * MPAD * 1024, bg + (size_t)l * MFF, nullptr, gbuf,
        MPAD, 1024, 1024, 1024, MPAD, MFF);
    gemm_bt<2><<<dim3(MPAD / 128, NROW / 128), 256, 0, stream>>>(
        h, WuT + (size_t)l * MPAD * 1024, bu + (size_t)l * MFF, nullptr, ubuf,
        MPAD, 1024, 1024, 1024, MPAD, MFF);
    // act = silu(g)*u (zero pad cols)
    swiglu_kernel<<<dim3(MPAD / 256, NROW), 256, 0, stream>>>(gbuf, ubuf, act);
    // x += act @ Wd + bd
    gemm_bt<1><<<dim3(1024 / 128, NROW / 128), 256, 0, stream>>>(
        act, WdT + (size_t)l * 1024 * MPAD, bd + (size_t)l * D_, x, x,
        1024, MPAD, MPAD, MPAD, 1024, 1024);
  }

  rmsnorm_final<<<dim3(B_), 256, 0, stream>>>(x, lnf, hfin);
  head_kernel<<<dim3(V_ / 64), 64, 0, stream>>>(hfin, Whead, bhead, out);
}

// Round 3
// 1450.411 us; speedup vs baseline: 1.4537x; 1.4537x over previous
//
#include <hip/hip_runtime.h>

#define B_   2
#define S_   1024
#define D_   1024
#define H_   16
#define HD_  64
#define L_   4
#define MFF  2730
#define MPAD 2816
#define V_   32000

typedef __attribute__((ext_vector_type(8))) short   short8;
typedef __attribute__((ext_vector_type(4))) float   floatx4;

__device__ __forceinline__ unsigned short f2b(float f) {
  unsigned u = __float_as_uint(f);
  u += 0x7fffu + ((u >> 16) & 1u);
  return (unsigned short)(u >> 16);
}
__device__ __forceinline__ float b2f(unsigned short s) {
  return __uint_as_float(((unsigned)s) << 16);
}

// async global->LDS, 16B per lane. LDS dst must be wave-uniform base; HW adds lane*16.
__device__ __forceinline__ void gload16(const unsigned short* g, unsigned short* l) {
  __builtin_amdgcn_global_load_lds(
      (const __attribute__((address_space(1))) unsigned int*)(unsigned long long)g,
      (__attribute__((address_space(3))) unsigned int*)(unsigned int)(unsigned long long)l,
      16, 0, 0);
}

// ---------------- embed gather ----------------
__global__ __launch_bounds__(256) void embed_kernel(const int* __restrict__ tokens,
                                                    const float* __restrict__ embed,
                                                    float* __restrict__ x) {
  int row = blockIdx.x;
  int tok = tokens[row];
  int c = threadIdx.x * 4;
  float4 v = *(const float4*)&embed[(size_t)tok * D_ + c];
  *(float4*)&x[(size_t)row * D_ + c] = v;
}

// ---------------- rmsnorm (f32 in -> bf16 out) ----------------
__global__ __launch_bounds__(256) void rmsnorm_bf(const float* __restrict__ x,
                                                  const float* __restrict__ w,
                                                  unsigned short* __restrict__ out) {
  int row = blockIdx.x, t = threadIdx.x;
  float4 xv = *(const float4*)&x[(size_t)row * D_ + t * 4];
  float ss = xv.x * xv.x + xv.y * xv.y + xv.z * xv.z + xv.w * xv.w;
  #pragma unroll
  for (int off = 1; off < 64; off <<= 1) ss += __shfl_xor(ss, off, 64);
  __shared__ float sred[4];
  if ((t & 63) == 0) sred[t >> 6] = ss;
  __syncthreads();
  ss = sred[0] + sred[1] + sred[2] + sred[3];
  float rr = rsqrtf(ss * (1.f / (float)D_) + 1e-6f);
  float4 wv = *(const float4*)&w[t * 4];
  size_t o = (size_t)row * D_ + t * 4;
  out[o + 0] = f2b(xv.x * rr * wv.x);
  out[o + 1] = f2b(xv.y * rr * wv.y);
  out[o + 2] = f2b(xv.z * rr * wv.z);
  out[o + 3] = f2b(xv.w * rr * wv.w);
}

// ---------------- final rmsnorm (last token rows, f32 out) ----------------
__global__ __launch_bounds__(256) void rmsnorm_final(const float* __restrict__ x,
                                                     const float* __restrict__ w,
                                                     float* __restrict__ out) {
  int b = blockIdx.x, t = threadIdx.x;
  const float* xr = x + ((size_t)b * S_ + (S_ - 1)) * D_;
  float4 xv = *(const float4*)&xr[t * 4];
  float ss = xv.x * xv.x + xv.y * xv.y + xv.z * xv.z + xv.w * xv.w;
  #pragma unroll
  for (int off = 1; off < 64; off <<= 1) ss += __shfl_xor(ss, off, 64);
  __shared__ float sred[4];
  if ((t & 63) == 0) sred[t >> 6] = ss;
  __syncthreads();
  ss = sred[0] + sred[1] + sred[2] + sred[3];
  float rr = rsqrtf(ss * (1.f / (float)D_) + 1e-6f);
  float4 wv = *(const float4*)&w[t * 4];
  size_t o = (size_t)b * D_ + t * 4;
  out[o + 0] = xv.x * rr * wv.x;
  out[o + 1] = xv.y * rr * wv.y;
  out[o + 2] = xv.z * rr * wv.z;
  out[o + 3] = xv.w * rr * wv.w;
}

// -------- weight transpose + f32->bf16, 64x64 tiles (K x N -> Npad x Kpad) --------
__global__ __launch_bounds__(256) void transpose_conv(const float* __restrict__ W,
                                                      unsigned short* __restrict__ Wt,
                                                      int K, int N, int Kpad, int Npad) {
  __shared__ float tile[64][65];
  const int tx = threadIdx.x & 15, ty = threadIdx.x >> 4;
  const int k0 = blockIdx.y * 64, n0 = blockIdx.x * 64;
  #pragma unroll
  for (int i = 0; i < 4; i++) {
    int kk = k0 + ty + i * 16;
    int nn = n0 + tx * 4;
    float4 v = {0.f, 0.f, 0.f, 0.f};
    if (kk < K) {
      if (nn + 3 < N) v = *(const float4*)&W[(size_t)kk * N + nn];
      else {
        if (nn + 0 < N) v.x = W[(size_t)kk * N + nn + 0];
        if (nn + 1 < N) v.y = W[(size_t)kk * N + nn + 1];
        if (nn + 2 < N) v.z = W[(size_t)kk * N + nn + 2];
      }
    }
    tile[ty + i * 16][tx * 4 + 0] = v.x;
    tile[ty + i * 16][tx * 4 + 1] = v.y;
    tile[ty + i * 16][tx * 4 + 2] = v.z;
    tile[ty + i * 16][tx * 4 + 3] = v.w;
  }
  __syncthreads();
  #pragma unroll
  for (int i = 0; i < 4; i++) {
    int nn = n0 + ty + i * 16;
    int kk = k0 + tx * 4;
    if (nn < Npad && kk < Kpad) {
      ushort4 o;
      o.x = f2b(tile[tx * 4 + 0][ty + i * 16]);
      o.y = f2b(tile[tx * 4 + 1][ty + i * 16]);
      o.z = f2b(tile[tx * 4 + 2][ty + i * 16]);
      o.w = f2b(tile[tx * 4 + 3][ty + i * 16]);
      *(ushort4*)&Wt[(size_t)nn * Kpad + kk] = o;
    }
  }
}

// ---- bf16 MFMA GEMM, A[M][K], B^T[N][K], MTILE x 128 tile, async LDS staging ----
// EPI: 0 = f32 out, 1 = f32 out + residual, 2 = bf16 out
template <int EPI, int MTILE>
__global__ __launch_bounds__(256) void gemm_bt(const unsigned short* __restrict__ A,
                                               const unsigned short* __restrict__ B,
                                               const float* __restrict__ bias,
                                               const float* __restrict__ res,
                                               void* __restrict__ Cout,
                                               int N, int K, int lda, int ldb, int ldc,
                                               int Nlog) {
  constexpr int MW = MTILE / 32;  // m-frags per wave
  __shared__ unsigned short As[MTILE * 32];
  __shared__ unsigned short Bs[128 * 32];
  const int tid = threadIdx.x;
  const int lane = tid & 63, wave = tid >> 6;
  const int m0 = blockIdx.y * MTILE, n0 = blockIdx.x * 128;
  const int rS = tid >> 2;
  const int kS = (tid & 3) * 8;
  const int fr = lane & 15;
  const int kq = (lane >> 4) * 8;
  const int wm = (wave & 1) * (MTILE / 2), wn = (wave >> 1) * 64;

  floatx4 zv = {0.f, 0.f, 0.f, 0.f};
  floatx4 acc[MW][4];
  #pragma unroll
  for (int mi = 0; mi < MW; mi++)
    #pragma unroll
    for (int ni = 0; ni < 4; ni++) acc[mi][ni] = zv;

  for (int k0 = 0; k0 < K; k0 += 32) {
    __syncthreads();
    #pragma unroll
    for (int i = 0; i < MTILE / 64; i++)
      gload16(A + (size_t)(m0 + i * 64 + rS) * lda + k0 + kS, &As[i * 2048 + wave * 512]);
    #pragma unroll
    for (int i = 0; i < 2; i++)
      gload16(B + (size_t)(n0 + i * 64 + rS) * ldb + k0 + kS, &Bs[i * 2048 + wave * 512]);
    __syncthreads();
    short8 af[MW], bfv[4];
    #pragma unroll
    for (int mi = 0; mi < MW; mi++) af[mi] = *(const short8*)&As[(wm + mi * 16 + fr) * 32 + kq];
    #pragma unroll
    for (int ni = 0; ni < 4; ni++) bfv[ni] = *(const short8*)&Bs[(wn + ni * 16 + fr) * 32 + kq];
    #pragma unroll
    for (int mi = 0; mi < MW; mi++)
      #pragma unroll
      for (int ni = 0; ni < 4; ni++)
        acc[mi][ni] = __builtin_amdgcn_mfma_f32_16x16x32_bf16(af[mi], bfv[ni], acc[mi][ni], 0, 0, 0);
  }

  const int cr = (lane >> 4) * 4;
  const int cc = lane & 15;
  #pragma unroll
  for (int mi = 0; mi < MW; mi++) {
    #pragma unroll
    for (int ni = 0; ni < 4; ni++) {
      int col = n0 + wn + ni * 16 + cc;
      float bv = (col < Nlog) ? bias[col] : 0.f;
      #pragma unroll
      for (int r = 0; r < 4; r++) {
        int row = m0 + wm + mi * 16 + cr + r;
        float val = acc[mi][ni][r] + bv;
        if constexpr (EPI == 1) val += res[(size_t)row * ldc + col];
        if constexpr (EPI == 2)
          ((unsigned short*)Cout)[(size_t)row * ldc + col] = f2b(val);
        else
          ((float*)Cout)[(size_t)row * ldc + col] = val;
      }
    }
  }
}

// ---------------- rope table (double precision) ----------------
__global__ __launch_bounds__(256) void rope_table(float* __restrict__ cs, float* __restrict__ sn) {
  int i = blockIdx.x * 256 + threadIdx.x;
  int s = i >> 5, f = i & 31;
  double inv = pow(10000.0, -(double)(2 * f) / 64.0);
  double ang = (double)s * inv;
  cs[i] = (float)cos(ang);
  sn[i] = (float)sin(ang);
}

// ------- rope apply (qkv bf16 -> q,k,v bf16 in (B*H,S,HD)) -------
__global__ __launch_bounds__(256) void rope_apply(const unsigned short* __restrict__ qkv,
                                                  const float* __restrict__ cs,
                                                  const float* __restrict__ sn,
                                                  unsigned short* __restrict__ q,
                                                  unsigned short* __restrict__ k,
                                                  unsigned short* __restrict__ v) {
  int i = blockIdx.x * 256 + threadIdx.x;  // B*S*H*32
  int pr = i & 31;
  int h  = (i >> 5) & 15;
  int s  = (i >> 9) & 1023;
  int b  = i >> 19;
  size_t base = ((size_t)(b * S_ + s)) * (3 * D_) + h * HD_ + pr * 2;
  unsigned qp = *(const unsigned*)&qkv[base];
  unsigned kp = *(const unsigned*)&qkv[base + D_];
  unsigned vp = *(const unsigned*)&qkv[base + 2 * D_];
  float qe = b2f((unsigned short)qp), qo = b2f((unsigned short)(qp >> 16));
  float ke = b2f((unsigned short)kp), ko = b2f((unsigned short)(kp >> 16));
  float c = cs[s * 32 + pr], sv = sn[s * 32 + pr];
  size_t ob = ((size_t)(b * H_ + h)) * (S_ * HD_) + (size_t)s * HD_ + pr * 2;
  unsigned qw = (unsigned)f2b(qe * c - qo * sv) | ((unsigned)f2b(qe * sv + qo * c) << 16);
  unsigned kw = (unsigned)f2b(ke * c - ko * sv) | ((unsigned)f2b(ke * sv + ko * c) << 16);
  *(unsigned*)&q[ob] = qw;
  *(unsigned*)&k[ob] = kw;
  *(unsigned*)&v[ob] = vp;
}

// ------- v transpose per bh: [bh][S][HD] -> [bh][HD][S] -------
__global__ __launch_bounds__(256) void vtrans(const unsigned short* __restrict__ v,
                                              unsigned short* __restrict__ vT) {
  __shared__ unsigned short t[64][72];
  const int st = blockIdx.x, bh = blockIdx.y;
  const int row = threadIdx.x >> 2, c = (threadIdx.x & 3) * 16;
  const unsigned short* vb = v + (size_t)bh * (S_ * HD_);
  unsigned short* vo = vT + (size_t)bh * (HD_ * S_);
  *(uint4*)&t[row][c]     = *(const uint4*)&vb[(size_t)(st * 64 + row) * HD_ + c];
  *(uint4*)&t[row][c + 8] = *(const uint4*)&vb[(size_t)(st * 64 + row) * HD_ + c + 8];
  __syncthreads();
  unsigned short buf[16];
  #pragma unroll
  for (int j = 0; j < 16; j++) buf[j] = t[c + j][row];
  *(uint4*)&vo[(size_t)row * S_ + st * 64 + c]     = *(uint4*)&buf[0];
  *(uint4*)&vo[(size_t)row * S_ + st * 64 + c + 8] = *(uint4*)&buf[8];
}

// ------- MFMA flash attention: q,k [bh][S][64] bf16, vT [bh][64][S] bf16 -> out bf16 (B,S,D)
__global__ __launch_bounds__(256) void attn_mfma(const unsigned short* __restrict__ qg,
                                                 const unsigned short* __restrict__ kg,
                                                 const unsigned short* __restrict__ vTg,
                                                 unsigned short* __restrict__ o) {
  __shared__ unsigned short ks[64 * 72];  // [kcol][d]
  __shared__ unsigned short vs[64 * 72];  // [d][kcol]
  __shared__ unsigned short ps[64 * 72];  // [qrow][kcol]
  const int qt = (S_ / 64 - 1) - blockIdx.x;  // heavy tiles first
  const int bh = blockIdx.y;
  const int b = bh >> 4, h = bh & 15;
  const unsigned short* qb = qg + (size_t)bh * (S_ * HD_);
  const unsigned short* kb = kg + (size_t)bh * (S_ * HD_);
  const unsigned short* vb = vTg + (size_t)bh * (HD_ * S_);
  const int tid = threadIdx.x, lane = tid & 63, wave = tid >> 6;
  const int fr = lane & 15;
  const int kq8 = (lane >> 4) * 8;
  const int srow = tid >> 2;
  const int sc = (tid & 3) * 16;

  short8 qf[2];
  {
    const int qrow = qt * 64 + wave * 16 + fr;
    qf[0] = *(const short8*)&qb[(size_t)qrow * HD_ + kq8];
    qf[1] = *(const short8*)&qb[(size_t)qrow * HD_ + 32 + kq8];
  }
  floatx4 zv = {0.f, 0.f, 0.f, 0.f};
  float m_run[4], l_run[4];
  floatx4 oacc[4];
  #pragma unroll
  for (int r = 0; r < 4; r++) { m_run[r] = -1e30f; l_run[r] = 0.f; }
  #pragma unroll
  for (int di = 0; di < 4; di++) oacc[di] = zv;

  const int rbase = wave * 16 + (lane >> 4) * 4;  // q row base within tile (per lane)

  for (int kt = 0; kt <= qt; kt++) {
    if (kt) __syncthreads();
    {
      const unsigned short* kr = &kb[(size_t)(kt * 64 + srow) * HD_ + sc];
      *(uint4*)&ks[srow * 72 + sc]     = *(const uint4*)kr;
      *(uint4*)&ks[srow * 72 + sc + 8] = *(const uint4*)(kr + 8);
      const unsigned short* vr = &vb[(size_t)srow * S_ + kt * 64 + sc];
      *(uint4*)&vs[srow * 72 + sc]     = *(const uint4*)vr;
      *(uint4*)&vs[srow * 72 + sc + 8] = *(const uint4*)(vr + 8);
    }
    __syncthreads();
    floatx4 s4[4];
    #pragma unroll
    for (int ni = 0; ni < 4; ni++) {
      short8 kf0 = *(const short8*)&ks[(ni * 16 + fr) * 72 + kq8];
      short8 kf1 = *(const short8*)&ks[(ni * 16 + fr) * 72 + 32 + kq8];
      floatx4 a = __builtin_amdgcn_mfma_f32_16x16x32_bf16(qf[0], kf0, zv, 0, 0, 0);
      s4[ni] = __builtin_amdgcn_mfma_f32_16x16x32_bf16(qf[1], kf1, a, 0, 0, 0);
    }
    const bool diag = (kt == qt);
    #pragma unroll
    for (int r = 0; r < 4; r++) {
      float sr[4];
      #pragma unroll
      for (int ni = 0; ni < 4; ni++) {
        float sv = s4[ni][r] * 0.125f;
        if (diag && (ni * 16 + fr > rbase + r)) sv = -1e9f;
        sr[ni] = sv;
      }
      float mx = fmaxf(fmaxf(sr[0], sr[1]), fmaxf(sr[2], sr[3]));
      #pragma unroll
      for (int off = 1; off < 16; off <<= 1) mx = fmaxf(mx, __shfl_xor(mx, off, 64));
      float mn = fmaxf(m_run[r], mx);
      float alpha = __expf(m_run[r] - mn);
      float rs = 0.f;
      #pragma unroll
      for (int ni = 0; ni < 4; ni++) {
        float pv = __expf(sr[ni] - mn);
        rs += pv;
        ps[(rbase + r) * 72 + ni * 16 + fr] = f2b(pv);
      }
      #pragma unroll
      for (int off = 1; off < 16; off <<= 1) rs += __shfl_xor(rs, off, 64);
      l_run[r] = l_run[r] * alpha + rs;
      m_run[r] = mn;
      #pragma unroll
      for (int di = 0; di < 4; di++) oacc[di][r] *= alpha;
    }
    #pragma unroll
    for (int kp = 0; kp < 2; kp++) {
      short8 pa = *(const short8*)&ps[(wave * 16 + fr) * 72 + kp * 32 + kq8];
      #pragma unroll
      for (int di = 0; di < 4; di++) {
        short8 vf = *(const short8*)&vs[(di * 16 + fr) * 72 + kp * 32 + kq8];
        oacc[di] = __builtin_amdgcn_mfma_f32_16x16x32_bf16(pa, vf, oacc[di], 0, 0, 0);
      }
    }
  }
  float inv[4];
  #pragma unroll
  for (int r = 0; r < 4; r++) inv[r] = 1.f / l_run[r];
  #pragma unroll
  for (int di = 0; di < 4; di++) {
    #pragma unroll
    for (int r = 0; r < 4; r++) {
      int srow_g = qt * 64 + rbase + r;
      o[((size_t)(b * S_ + srow_g)) * D_ + h * HD_ + di * 16 + fr] = f2b(oacc[di][r] * inv[r]);
    }
  }
}

// ------- bias concat for fused gate/up GEMM -------
__global__ __launch_bounds__(256) void concat_bias(const float* __restrict__ bg_,
                                                   const float* __restrict__ bu_,
                                                   float* __restrict__ bgu) {
  int n = blockIdx.x * 256 + threadIdx.x;  // 0..2*MPAD-1
  float v = 0.f;
  if (n < MPAD) { if (n < MFF) v = bg_[n]; }
  else { int m = n - MPAD; if (m < MFF) v = bu_[m]; }
  bgu[n] = v;
}

// ------- swiglu: act[row][n] = silu(g)*u from fused gu buffer -------
__global__ __launch_bounds__(256) void swiglu_kernel(const unsigned short* __restrict__ gu,
                                                     unsigned short* __restrict__ act) {
  int n = blockIdx.x * 256 + threadIdx.x;
  int row = blockIdx.y;
  float a = 0.f;
  if (n < MFF) {
    float gv = b2f(gu[(size_t)row * (2 * MPAD) + n]);
    float uv = b2f(gu[(size_t)row * (2 * MPAD) + MPAD + n]);
    a = gv / (1.f + __expf(-gv)) * uv;
  }
  act[(size_t)row * MPAD + n] = f2b(a);
}

// ------- head GEMV, 256 threads, 4-way k-split -------
__global__ __launch_bounds__(256) void head_kernel(const float* __restrict__ hf,
                                                   const float* __restrict__ Wh,
                                                   const float* __restrict__ bh_,
                                                   float* __restrict__ out) {
  __shared__ float hs[2 * D_];
  __shared__ float r0[256], r1[256];
  int t = threadIdx.x;
  for (int i = t; i < 2 * D_; i += 256) hs[i] = hf[i];
  __syncthreads();
  int col = blockIdx.x * 64 + (t & 63);
  int ksl = t >> 6;
  float a0 = 0.f, a1 = 0.f;
  for (int k = ksl * 256; k < ksl * 256 + 256; k++) {
    float w = Wh[(size_t)k * V_ + col];
    a0 = fmaf(hs[k], w, a0);
    a1 = fmaf(hs[D_ + k], w, a1);
  }
  r0[t] = a0; r1[t] = a1;
  __syncthreads();
  if (t < 64) {
    int c = blockIdx.x * 64 + t;
    out[c]      = r0[t] + r0[t + 64] + r0[t + 128] + r0[t + 192] + bh_[c];
    out[V_ + c] = r1[t] + r1[t + 64] + r1[t + 128] + r1[t + 192] + bh_[c];
  }
}

// ======================= launcher =======================
extern "C" void kernel_launch(void* const* d_in, const int* in_sizes, int n_in,
                              void* d_out, int out_size, void* d_ws, size_t ws_size,
                              hipStream_t stream) {
  const int*   tokens = (const int*)d_in[0];
  const float* embed  = (const float*)d_in[1];
  const float* Wqkv   = (const float*)d_in[2];
  const float* bqkv   = (const float*)d_in[3];
  const float* Wout   = (const float*)d_in[4];
  const float* bout   = (const float*)d_in[5];
  const float* ln1    = (const float*)d_in[6];
  const float* ln2    = (const float*)d_in[7];
  const float* Wg     = (const float*)d_in[8];
  const float* bg     = (const float*)d_in[9];
  const float* Wu     = (const float*)d_in[10];
  const float* bu     = (const float*)d_in[11];
  const float* Wd     = (const float*)d_in[12];
  const float* bd     = (const float*)d_in[13];
  const float* lnf    = (const float*)d_in[14];
  const float* Whead  = (const float*)d_in[15];
  const float* bhead  = (const float*)d_in[16];
  float* out = (float*)d_out;

  char* base = (char*)d_ws;
  size_t off = 0;
  auto alloc = [&](size_t bytes) -> char* {
    char* r = base + off;
    off += (bytes + 255) & ~(size_t)255;
    return r;
  };
  const size_t NROW = (size_t)B_ * S_;  // 2048
  unsigned short* WqkvT = (unsigned short*)alloc((size_t)L_ * 3072 * 1024 * 2);
  unsigned short* WoutT = (unsigned short*)alloc((size_t)L_ * 1024 * 1024 * 2);
  unsigned short* WguT  = (unsigned short*)alloc((size_t)L_ * 2 * MPAD * 1024 * 2);
  unsigned short* WdT   = (unsigned short*)alloc((size_t)L_ * 1024 * MPAD * 2);
  float*          x     = (float*)alloc(NROW * D_ * 4);
  unsigned short* h     = (unsigned short*)alloc(NROW * D_ * 2);
  unsigned short* qkv   = (unsigned short*)alloc(NROW * 3072 * 2);  // act aliases
  unsigned short* qb    = (unsigned short*)alloc(NROW * HD_ * H_ * 2);
  unsigned short* kb    = (unsigned short*)alloc(NROW * HD_ * H_ * 2);
  unsigned short* vb    = (unsigned short*)alloc(NROW * HD_ * H_ * 2);  // aout aliases
  unsigned short* vT    = (unsigned short*)alloc(NROW * HD_ * H_ * 2);
  unsigned short* gu    = (unsigned short*)alloc(NROW * 2 * MPAD * 2);
  float*          bgu   = (float*)alloc(2 * MPAD * 4);
  float*          csT   = (float*)alloc((size_t)S_ * 32 * 4);
  float*          snT   = (float*)alloc((size_t)S_ * 32 * 4);
  float*          hfin  = (float*)alloc((size_t)B_ * D_ * 4);
  unsigned short* act   = qkv;  // dead after rope_apply; reused after attention
  unsigned short* aout  = vb;   // dead after vtrans; reused as attention output

  // ---- weight transposes (per call; ws is re-poisoned) ----
  for (int l = 0; l < L_; l++) {
    transpose_conv<<<dim3(3072 / 64, 1024 / 64), 256, 0, stream>>>(
        Wqkv + (size_t)l * 1024 * 3072, WqkvT + (size_t)l * 3072 * 1024, 1024, 3072, 1024, 3072);
    transpose_conv<<<dim3(1024 / 64, 1024 / 64), 256, 0, stream>>>(
        Wout + (size_t)l * 1024 * 1024, WoutT + (size_t)l * 1024 * 1024, 1024, 1024, 1024, 1024);
    transpose_conv<<<dim3(MPAD / 64, 1024 / 64), 256, 0, stream>>>(
        Wg + (size_t)l * 1024 * MFF, WguT + (size_t)l * 2 * MPAD * 1024, 1024, MFF, 1024, MPAD);
    transpose_conv<<<dim3(MPAD / 64, 1024 / 64), 256, 0, stream>>>(
        Wu + (size_t)l * 1024 * MFF, WguT + (size_t)l * 2 * MPAD * 1024 + (size_t)MPAD * 1024,
        1024, MFF, 1024, MPAD);
    transpose_conv<<<dim3(1024 / 64, MPAD / 64), 256, 0, stream>>>(
        Wd + (size_t)l * MFF * 1024, WdT + (size_t)l * 1024 * MPAD, MFF, 1024, MPAD, 1024);
  }
  rope_table<<<dim3(S_ * 32 / 256), 256, 0, stream>>>(csT, snT);
  embed_kernel<<<dim3(NROW), 256, 0, stream>>>(tokens, embed, x);

  for (int l = 0; l < L_; l++) {
    rmsnorm_bf<<<dim3(NROW), 256, 0, stream>>>(x, ln1 + (size_t)l * D_, h);
    gemm_bt<2, 128><<<dim3(3072 / 128, NROW / 128), 256, 0, stream>>>(
        h, WqkvT + (size_t)l * 3072 * 1024, bqkv + (size_t)l * 3072, nullptr, qkv,
        3072, 1024, 1024, 1024, 3072, 3072);
    rope_apply<<<dim3((B_ * S_ * H_ * 32) / 256), 256, 0, stream>>>(qkv, csT, snT, qb, kb, vb);
    vtrans<<<dim3(S_ / 64, B_ * H_), 256, 0, stream>>>(vb, vT);
    attn_mfma<<<dim3(S_ / 64, B_ * H_), 256, 0, stream>>>(qb, kb, vT, aout);
    gemm_bt<1, 64><<<dim3(1024 / 128, NROW / 64), 256, 0, stream>>>(
        aout, WoutT + (size_t)l * 1024 * 1024, bout + (size_t)l * D_, x, x,
        1024, 1024, 1024, 1024, 1024, 1024);
    rmsnorm_bf<<<dim3(NROW), 256, 0, stream>>>(x, ln2 + (size_t)l * D_, h);
    concat_bias<<<dim3(2 * MPAD / 256), 256, 0, stream>>>(
        bg + (size_t)l * MFF, bu + (size_t)l * MFF, bgu);
    gemm_bt<2, 128><<<dim3(2 * MPAD / 128, NROW / 128), 256, 0, stream>>>(
        h, WguT + (size_t)l * 2 * MPAD * 1024, bgu, nullptr, gu,
        2 * MPAD, 1024, 1024, 1024, 2 * MPAD, 2 * MPAD);
    swiglu_kernel<<<dim3(MPAD / 256, NROW), 256, 0, stream>>>(gu, act);
    gemm_bt<1, 64><<<dim3(1024 / 128, NROW / 64), 256, 0, stream>>>(
        act, WdT + (size_t)l * 1024 * MPAD, bd + (size_t)l * D_, x, x,
        1024, MPAD, MPAD, MPAD, 1024, 1024);
  }

  rmsnorm_final<<<dim3(B_), 256, 0, stream>>>(x, lnf, hfin);
  head_kernel<<<dim3(V_ / 64), 256, 0, stream>>>(hfin, Whead, bhead, out);
}